// Round 2
// baseline (3179.924 us; speedup 1.0000x reference)
//
#include <hip/hip_runtime.h>

#define T_DIM 16

// ---------------- conv3d stride(1,2,2) pad 1, thread tile NCO co x 4 w ----------------
template<int CI,int HI,int WI,int CO,int HO,int WO,int NCO,bool RELU>
__global__ void conv3d_s122_k(const float* __restrict__ in, const float* __restrict__ wgt,
                              const float* __restrict__ bias, float* __restrict__ out) {
  const int tx = threadIdx.x;
  const int w0 = tx * 4;
  const int h  = blockIdx.x * blockDim.y + threadIdx.y;
  const int co0 = blockIdx.y * NCO;
  const int bz = blockIdx.z;
  const int b = bz >> 4, t = bz & 15;

  float acc[NCO][4];
  #pragma unroll
  for (int i = 0; i < NCO; ++i) {
    const float bv = bias[co0 + i];
    #pragma unroll
    for (int j = 0; j < 4; ++j) acc[i][j] = bv;
  }
  const int cs = 2 * w0 - 2;

  for (int ci = 0; ci < CI; ++ci) {
    const float* inc = in + (size_t)((b * CI + ci) * T_DIM) * (HI * WI);
    const float* wc  = wgt + ((size_t)co0 * CI + ci) * 27;
    #pragma unroll
    for (int kd = 0; kd < 3; ++kd) {
      const int t2 = t - 1 + kd;
      if (t2 < 0 || t2 >= T_DIM) continue;
      const float* ip = inc + t2 * (HI * WI);
      #pragma unroll
      for (int kh = 0; kh < 3; ++kh) {
        const int hh = 2 * h - 1 + kh;
        float v[10];
        if (hh >= 0) {
          const float* r = ip + hh * WI + cs;
          if (cs >= 0) { float2 u = *(const float2*)r; v[0] = u.x; v[1] = u.y; }
          else         { v[0] = 0.f; v[1] = 0.f; }
          float2 u1 = *(const float2*)(r + 2); v[2] = u1.x; v[3] = u1.y;
          float2 u2 = *(const float2*)(r + 4); v[4] = u2.x; v[5] = u2.y;
          float2 u3 = *(const float2*)(r + 6); v[6] = u3.x; v[7] = u3.y;
          float2 u4 = *(const float2*)(r + 8); v[8] = u4.x; v[9] = u4.y;
        } else {
          #pragma unroll
          for (int z = 0; z < 10; ++z) v[z] = 0.f;
        }
        #pragma unroll
        for (int i = 0; i < NCO; ++i) {
          const float* wp = wc + (size_t)i * (CI * 27) + kd * 9 + kh * 3;
          const float wa = wp[0], wb = wp[1], wcc = wp[2];
          #pragma unroll
          for (int wi = 0; wi < 4; ++wi) {
            acc[i][wi] = fmaf(v[1 + 2*wi], wa,  acc[i][wi]);
            acc[i][wi] = fmaf(v[2 + 2*wi], wb,  acc[i][wi]);
            acc[i][wi] = fmaf(v[3 + 2*wi], wcc, acc[i][wi]);
          }
        }
      }
    }
  }
  #pragma unroll
  for (int i = 0; i < NCO; ++i) {
    float4 o;
    float* po = (float*)&o;
    #pragma unroll
    for (int j = 0; j < 4; ++j) {
      float x = acc[i][j];
      if (RELU) x = fmaxf(x, 0.f);
      po[j] = x;
    }
    *(float4*)(out + ((size_t)(((b * CO + co0 + i) * T_DIM + t) * HO + h)) * WO + w0) = o;
  }
}

// ---------------- codebook transpose: cbt[c][v] = cb[v][c] ----------------
__global__ void transpose_cb_k(const float* __restrict__ cb, float* __restrict__ cbt) {
  __shared__ float tile[32][33];
  const int v0 = blockIdx.x * 32, c0 = blockIdx.y * 32;
  const int tx = threadIdx.x, ty = threadIdx.y;   // (32,8)
  #pragma unroll
  for (int r = 0; r < 32; r += 8)
    tile[ty + r][tx] = cb[(size_t)(v0 + ty + r) * 512 + c0 + tx];
  __syncthreads();
  #pragma unroll
  for (int r = 0; r < 32; r += 8)
    cbt[(size_t)(c0 + ty + r) * 8192 + v0 + tx] = tile[tx][ty + r];
}

// ---------------- codebook squared norms ----------------
__global__ void c2_k(const float* __restrict__ cb, float* __restrict__ c2) {
  const int wid = threadIdx.x >> 6, lane = threadIdx.x & 63;
  const int v = blockIdx.x * 4 + wid;
  const float* row = cb + (size_t)v * 512 + lane * 8;
  float4 a = *(const float4*)row, b = *(const float4*)(row + 4);
  float s = a.x*a.x + a.y*a.y + a.z*a.z + a.w*a.w
          + b.x*b.x + b.y*b.y + b.z*b.z + b.w*b.w;
  #pragma unroll
  for (int off = 32; off; off >>= 1) s += __shfl_down(s, off);
  if (lane == 0) c2[v] = s;
}

// ---------------- VQ: fused GEMM (dist = c2 - 2*dot) + argmin ----------------
#define VQ_KC 16
__global__ void vq_k(const float* __restrict__ f,    // [B][512][4096]
                     const float* __restrict__ cbt,  // [512][8192]
                     const float* __restrict__ c2,
                     float* __restrict__ pval, int* __restrict__ pidx) {
  __shared__ float A[VQ_KC][68];
  __shared__ float Bs[VQ_KC][132];
  const int tid = threadIdx.x;       // 0..127
  const int tx = tid & 15, ty = tid >> 4;
  const int sc = blockIdx.x;         // 0..15 superchunk of 512 v
  const int tb = blockIdx.y;         // 0..127 token block (64 tokens)
  const int b = tb >> 6;
  const int n0 = (tb & 63) * 64;
  const float* fb = f + (size_t)b * 512 * 4096;

  const int skk = tid >> 3;          // 0..15
  const int sA = (tid & 7) * 8;
  const int sB = (tid & 7) * 16;

  float best[8]; int bidx[8];
  #pragma unroll
  for (int i = 0; i < 8; ++i) { best[i] = 3.4e38f; bidx[i] = 0; }

  for (int vt = 0; vt < 4; ++vt) {
    const int v0 = sc * 512 + vt * 128;
    float acc[8][8];
    #pragma unroll
    for (int i = 0; i < 8; ++i)
      #pragma unroll
      for (int j = 0; j < 8; ++j) acc[i][j] = 0.f;

    for (int k0 = 0; k0 < 512; k0 += VQ_KC) {
      __syncthreads();
      {
        const float* src = fb + (size_t)(k0 + skk) * 4096 + n0 + sA;
        *(float4*)&A[skk][sA]     = *(const float4*)src;
        *(float4*)&A[skk][sA + 4] = *(const float4*)(src + 4);
      }
      {
        const float* src = cbt + (size_t)(k0 + skk) * 8192 + v0 + sB;
        *(float4*)&Bs[skk][sB]      = *(const float4*)src;
        *(float4*)&Bs[skk][sB + 4]  = *(const float4*)(src + 4);
        *(float4*)&Bs[skk][sB + 8]  = *(const float4*)(src + 8);
        *(float4*)&Bs[skk][sB + 12] = *(const float4*)(src + 12);
      }
      __syncthreads();
      #pragma unroll
      for (int kk = 0; kk < VQ_KC; ++kk) {
        float a[8], bv[8];
        *(float4*)&a[0]  = *(float4*)&A[kk][ty * 8];
        *(float4*)&a[4]  = *(float4*)&A[kk][ty * 8 + 4];
        *(float4*)&bv[0] = *(float4*)&Bs[kk][tx * 4];
        *(float4*)&bv[4] = *(float4*)&Bs[kk][64 + tx * 4];
        #pragma unroll
        for (int i = 0; i < 8; ++i)
          #pragma unroll
          for (int j = 0; j < 8; ++j)
            acc[i][j] = fmaf(a[i], bv[j], acc[i][j]);
      }
    }
    float cc[8];
    *(float4*)&cc[0] = *(const float4*)(c2 + v0 + tx * 4);
    *(float4*)&cc[4] = *(const float4*)(c2 + v0 + 64 + tx * 4);
    #pragma unroll
    for (int j = 0; j < 8; ++j) {
      const int vg = v0 + ((j < 4) ? (tx * 4 + j) : (64 + tx * 4 + (j - 4)));
      #pragma unroll
      for (int i = 0; i < 8; ++i) {
        const float d = cc[j] - 2.f * acc[i][j];
        if (d < best[i] || (d == best[i] && vg < bidx[i])) { best[i] = d; bidx[i] = vg; }
      }
    }
  }
  #pragma unroll
  for (int off = 1; off < 16; off <<= 1) {
    #pragma unroll
    for (int i = 0; i < 8; ++i) {
      const float ov = __shfl_xor(best[i], off);
      const int   oi = __shfl_xor(bidx[i], off);
      if (ov < best[i] || (ov == best[i] && oi < bidx[i])) { best[i] = ov; bidx[i] = oi; }
    }
  }
  if (tx == 0) {
    #pragma unroll
    for (int i = 0; i < 8; ++i) {
      const int tok = tb * 64 + ty * 8 + i;
      pval[(size_t)tok * 16 + sc] = best[i];
      pidx[(size_t)tok * 16 + sc] = bidx[i];
    }
  }
}

__global__ void vq_reduce_k(const float* __restrict__ pval, const int* __restrict__ pidx,
                            int* __restrict__ tokens, float* __restrict__ out_tok) {
  const int tok = blockIdx.x * blockDim.x + threadIdx.x;  // 8192
  float best = 3.4e38f; int bi = 0;
  for (int s = 0; s < 16; ++s) {
    const float v = pval[(size_t)tok * 16 + s];
    const int idx = pidx[(size_t)tok * 16 + s];
    if (v < best || (v == best && idx < bi)) { best = v; bi = idx; }
  }
  tokens[tok] = bi;
  out_tok[tok] = (float)bi;
}

__global__ void gather_k(const int* __restrict__ tokens, const float* __restrict__ emb,
                         float* __restrict__ out) {
  const int i = blockIdx.x * blockDim.x + threadIdx.x;  // 1,048,576 float4s
  const int n = i >> 7;
  const int c4 = (i & 127) * 4;
  const int tk = tokens[n];
  float4 v = *(const float4*)(emb + (size_t)tk * 512 + c4);
  *(float4*)(out + (size_t)n * 512 + c4) = v;
}

extern "C" void kernel_launch(void* const* d_in, const int* in_sizes, int n_in,
                              void* d_out, int out_size, void* d_ws, size_t ws_size,
                              hipStream_t stream) {
  const float* video = (const float*)d_in[0];
  const float* w1 = (const float*)d_in[1];
  const float* b1 = (const float*)d_in[2];
  const float* w2 = (const float*)d_in[3];
  const float* b2 = (const float*)d_in[4];
  const float* w3 = (const float*)d_in[5];
  const float* b3 = (const float*)d_in[6];
  const float* cb  = (const float*)d_in[7];
  const float* emb = (const float*)d_in[8];

  // ---- workspace layout (floats) ----
  // region A: ws[0 .. 16,777,216)  = h1 (conv1 out / conv2 in).
  //   After conv2 this region is DEAD and is reused:
  //     f   = ws[0          .. 4,194,304)   (conv3 out; conv3 reads h2, no overlap)
  //     cbt = ws[4,194,304  .. 8,388,608)   (written after conv2 on same stream)
  //     c2  = ws[8,388,608  .. 8,396,800)
  // region B: ws[16,777,216 .. 25,165,824) = h2 (conv2 out / conv3 in)  [8,388,608 floats]
  // region C: pval/pidx/tokens after h2
  float* ws = (float*)d_ws;
  float* h1   = ws;
  float* f    = ws;
  float* cbt  = ws + 4194304;
  float* c2   = ws + 8388608;
  float* h2   = ws + 16777216;
  float* pval = ws + 25165824;            //   131,072
  int*   pidx = (int*)(pval + 131072);    //   131,072
  int*   tokens = pidx + 131072;          //     8,192
  float* out_tok = (float*)d_out;
  float* out_emb = (float*)d_out + 8192;

  hipLaunchKernelGGL((conv3d_s122_k<3, 128, 128, 128, 64, 64, 8, true>),
                     dim3(4, 16, 32), dim3(16, 16), 0, stream, video, w1, b1, h1);
  hipLaunchKernelGGL((conv3d_s122_k<128, 64, 64, 256, 32, 32, 8, true>),
                     dim3(1, 32, 32), dim3(8, 32), 0, stream, h1, w2, b2, h2);
  // h1 dead from here; cbt/c2/f live in its space
  hipLaunchKernelGGL(transpose_cb_k, dim3(256, 16), dim3(32, 8), 0, stream, cb, cbt);
  hipLaunchKernelGGL(c2_k, dim3(2048), dim3(256), 0, stream, cb, c2);
  hipLaunchKernelGGL((conv3d_s122_k<256, 32, 32, 512, 16, 16, 8, false>),
                     dim3(1, 64, 32), dim3(4, 16), 0, stream, h2, w3, b3, f);
  hipLaunchKernelGGL(vq_k, dim3(16, 128), dim3(128), 0, stream, f, cbt, c2, pval, pidx);
  hipLaunchKernelGGL(vq_reduce_k, dim3(32), dim3(256), 0, stream, pval, pidx, tokens, out_tok);
  hipLaunchKernelGGL(gather_k, dim3(4096), dim3(256), 0, stream, tokens, emb, out_emb);
}